// Round 3
// baseline (484.800 us; speedup 1.0000x reference)
//
#include <hip/hip_runtime.h>

typedef unsigned long long u64;
typedef unsigned int u32;

#define MAXD 5
#define BSH  6
#define BN   64        // nodes per bucket
#define NTH  256
#define CAPG 2816      // bucket-major record capacity (mean 2046, +17 sigma)
#define HEMPTY 0xFFFFFFFFu

// ---------------------------------------------------------------------------
// R14: R2 proved barriers must be dispatch boundaries (782 x threadfence =
// wbL2 storm, 3x slower). So keep multi-kernel, but delete the WORK:
// chunk_sort + level12_merge (LDS hist/scan/placement + 40MB random merge
// refetch) are replaced by ONE direct scatter kernel: per record,
// atomicAdd(&bucketCur[b],1) -> agent-scope (sc1 write-through) store into
// bucket-major recs2. 1.6M atomics over 782 counters ~ a few us at the TCCs;
// write-through avoids cross-XCD partial-line writeback clobber. Depth 2
// becomes a light kernel identical to the proven level3 pattern.
//
// Dispatches: memset(NFg+bucketCur) | build_scatter | depth2_init |
//             level3 | level4_fin
// ws: NFg[N] (u64) bucketCur[NB] (u32) | V CNT F2 F3 [N] (u64) |
//     srcPack[64] nvalid (u32) | recs2[NB*CAPG] (u32)
// ---------------------------------------------------------------------------

__global__ __launch_bounds__(NTH) void build_scatter(
    const int* __restrict__ h, const int* __restrict__ t, int E,
    const int* __restrict__ anchor, int A,
    u64* __restrict__ NFg, u32* __restrict__ srcPack, int* __restrict__ nvalid,
    u32* __restrict__ bucketCur, u32* __restrict__ recs2) {
    __shared__ u32 hsKey[128], hsBit[128];
    int tid = threadIdx.x, b = blockIdx.x;
    if (tid < 128) hsKey[tid] = HEMPTY;
    __syncthreads();

    if (tid < 64) {  // wave 0: anchor gather + shfl dedup + hash insert
        int K = 2 * A;
        int a_ = (tid < K) ? anchor[(tid < A) ? tid : (tid - A)] : 0;
        int my = (tid < K) ? ((tid < A) ? h[a_] : t[a_]) : -1;
        bool uniq = (tid < K);
        for (int j = 0; j < 64; ++j) {
            int o = __shfl(my, j, 64);
            if (j < tid && o == my) uniq = false;
        }
        u64 mask = __ballot(uniq);
        if (b == 0 && tid == 0) *nvalid = (int)__popcll(mask);
        if (uniq) {
            u32 slot = ((u32)my * 2654435761u) >> 25;
            while (atomicCAS(&hsKey[slot], HEMPTY, (u32)my) != HEMPTY)
                slot = (slot + 1) & 127u;
            hsBit[slot] = (u32)tid;
        }
        if (b == 0)
            srcPack[tid] = uniq ? (((u32)my << BSH) | (u32)tid) : HEMPTY;
    }
    __syncthreads();

    auto srcMask = [&](u32 src) -> u64 {
        u32 slot = (src * 2654435761u) >> 25;
        while (true) {
            u32 k = hsKey[slot];
            if (k == src) return 1ull << hsBit[slot];
            if (k == HEMPTY) return 0ull;
            slot = (slot + 1) & 127u;
        }
    };

    // block owns 1024 consecutive edges, 4 per thread (coalesced, ILP=4)
    int base = b * (4 * NTH);
#pragma unroll
    for (int k = 0; k < 4; ++k) {
        int i = base + k * NTH + tid;
        if (i < E) {
            u32 uu = (u32)h[i], vv = (u32)t[i];
            u32 b1 = vv >> BSH, b2 = uu >> BSH;
            u32 p1 = atomicAdd(&bucketCur[b1], 1u);
            u32 p2 = atomicAdd(&bucketCur[b2], 1u);
            if (p1 < CAPG)
                __hip_atomic_store(&recs2[(u32)b1 * CAPG + p1],
                                   (uu << BSH) | (vv & (BN - 1)),
                                   __ATOMIC_RELAXED, __HIP_MEMORY_SCOPE_AGENT);
            if (p2 < CAPG)
                __hip_atomic_store(&recs2[(u32)b2 * CAPG + p2],
                                   (vv << BSH) | (uu & (BN - 1)),
                                   __ATOMIC_RELAXED, __HIP_MEMORY_SCOPE_AGENT);
            if (uu != vv) {   // self-loop guard keeps NFg == depth-1 exactly
                u64 m1 = srcMask(uu);
                if (m1) atomicOr(&NFg[vv], m1);
                u64 m2 = srcMask(vv);
                if (m2) atomicOr(&NFg[uu], m2);
            }
        }
    }
}

// Depth 2 + V/CNT init: contiguous bucket-major gather (level3 pattern).
__global__ __launch_bounds__(NTH) void depth2_init(
    const u32* __restrict__ recs2, const u32* __restrict__ bucketCur,
    const u32* __restrict__ srcPack, const u64* __restrict__ NFg,
    u64* __restrict__ F2, u64* __restrict__ V, u64* __restrict__ CNT, int N) {
    __shared__ u64 NF[BN];
    __shared__ u32 srcL[64];
    int b = blockIdx.x, tid = threadIdx.x;
    if (tid < BN) NF[tid] = 0ull;
    if (tid < 64) srcL[tid] = srcPack[tid];
    __syncthreads();
    u32 cnt = min(bucketCur[b], (u32)CAPG);
    u32 o0 = (u32)b * CAPG;
    u32 r = tid;
    for (; r + 3u * NTH < cnt; r += 4u * NTH) {
        u32 c0 = recs2[o0 + r],           c1 = recs2[o0 + r + NTH];
        u32 c2 = recs2[o0 + r + 2 * NTH], c3 = recs2[o0 + r + 3 * NTH];
        u64 f0 = NFg[c0 >> BSH], f1 = NFg[c1 >> BSH];
        u64 f2 = NFg[c2 >> BSH], f3 = NFg[c3 >> BSH];
        if (f0) atomicOr(&NF[c0 & (BN - 1)], f0);
        if (f1) atomicOr(&NF[c1 & (BN - 1)], f1);
        if (f2) atomicOr(&NF[c2 & (BN - 1)], f2);
        if (f3) atomicOr(&NF[c3 & (BN - 1)], f3);
    }
    for (; r < cnt; r += NTH) {
        u32 c0 = recs2[o0 + r];
        u64 f0 = NFg[c0 >> BSH];
        if (f0) atomicOr(&NF[c0 & (BN - 1)], f0);
    }
    __syncthreads();
    if (tid < BN) {
        int n = b * BN + tid;
        if (n < N) {
            u64 srcbit = 0ull;
            for (int k = 0; k < 64; ++k) {
                u32 pk = srcL[k];
                if (pk != HEMPTY && (int)(pk >> BSH) == n)
                    srcbit |= 1ull << (pk & (BN - 1));
            }
            u64 nf1 = NFg[n];
            u64 v1 = srcbit | nf1;
            u64 newly2 = NF[tid] & ~v1;
            V[n] = v1 | newly2;
            F2[n] = newly2;
            CNT[n] = (srcbit ? 1ull : 0ull)
                   | ((u64)__popcll(nf1) << 8)
                   | ((u64)__popcll(newly2) << 16);
        }
    }
}

// Depth 3: contiguous bucket-major gather, 4-wide unrolled.
__global__ __launch_bounds__(NTH) void level3(
    const u32* __restrict__ recs2, const u32* __restrict__ bucketCur,
    const u64* __restrict__ Fin, u64* __restrict__ Fout,
    u64* __restrict__ V, u64* __restrict__ CNT, int N) {
    __shared__ u64 NF[BN];
    int b = blockIdx.x, tid = threadIdx.x;
    u32 o0 = (u32)b * CAPG;
    u32 cnt = min(bucketCur[b], (u32)CAPG);
    if (tid < BN) NF[tid] = 0ull;
    __syncthreads();
    u32 r = tid;
    for (; r + 3u * NTH < cnt; r += 4u * NTH) {
        u32 c0 = recs2[o0 + r],           c1 = recs2[o0 + r + NTH];
        u32 c2 = recs2[o0 + r + 2 * NTH], c3 = recs2[o0 + r + 3 * NTH];
        u64 f0 = Fin[c0 >> BSH], f1 = Fin[c1 >> BSH];
        u64 f2 = Fin[c2 >> BSH], f3 = Fin[c3 >> BSH];
        if (f0) atomicOr(&NF[c0 & (BN - 1)], f0);
        if (f1) atomicOr(&NF[c1 & (BN - 1)], f1);
        if (f2) atomicOr(&NF[c2 & (BN - 1)], f2);
        if (f3) atomicOr(&NF[c3 & (BN - 1)], f3);
    }
    for (; r < cnt; r += NTH) {
        u32 c0 = recs2[o0 + r];
        u64 f0 = Fin[c0 >> BSH];
        if (f0) atomicOr(&NF[c0 & (BN - 1)], f0);
    }
    __syncthreads();
    if (tid < BN) {
        int n = b * BN + tid;
        if (n < N) {
            u64 vis = V[n];
            u64 newly = NF[tid] & ~vis;
            Fout[n] = newly;
            if (newly) {
                V[n] = vis | newly;
                CNT[n] += (u64)__popcll(newly) << 24;
            }
        }
    }
}

// Depth 4 fused with the output matmul (quad lane q writes float4 q, D=16).
__global__ __launch_bounds__(NTH) void level4_fin(
    const u32* __restrict__ recs2, const u32* __restrict__ bucketCur,
    const u64* __restrict__ Fin, const u64* __restrict__ V,
    const u64* __restrict__ CNT, const int* __restrict__ nvalid,
    const float* __restrict__ embed, float* __restrict__ out, int N) {
    __shared__ u64 NF[BN];
    int b = blockIdx.x, tid = threadIdx.x;
    u32 o0 = (u32)b * CAPG;
    u32 cnt = min(bucketCur[b], (u32)CAPG);
    if (tid < BN) NF[tid] = 0ull;
    __syncthreads();
    u32 r = tid;
    for (; r + 3u * NTH < cnt; r += 4u * NTH) {
        u32 c0 = recs2[o0 + r],           c1 = recs2[o0 + r + NTH];
        u32 c2 = recs2[o0 + r + 2 * NTH], c3 = recs2[o0 + r + 3 * NTH];
        u64 f0 = Fin[c0 >> BSH], f1 = Fin[c1 >> BSH];
        u64 f2 = Fin[c2 >> BSH], f3 = Fin[c3 >> BSH];
        if (f0) atomicOr(&NF[c0 & (BN - 1)], f0);
        if (f1) atomicOr(&NF[c1 & (BN - 1)], f1);
        if (f2) atomicOr(&NF[c2 & (BN - 1)], f2);
        if (f3) atomicOr(&NF[c3 & (BN - 1)], f3);
    }
    for (; r < cnt; r += NTH) {
        u32 c0 = recs2[o0 + r];
        u64 f0 = Fin[c0 >> BSH];
        if (f0) atomicOr(&NF[c0 & (BN - 1)], f0);
    }
    __syncthreads();
    int nl = tid >> 2, q = tid & 3;   // 64 nodes x 4 float4 quads (D=16)
    int n = b * BN + nl;
    if (n >= N) return;
    u64 vis = V[n];
    int c4 = __popcll(NF[nl] & ~vis);
    u64 c = CNT[n];
    int nv = *nvalid;
    float inv = 1.0f / (float)(nv > 0 ? nv : 1);
    float cd[MAXD + 1];
    int total = c4;
#pragma unroll
    for (int d = 0; d < 4; ++d) {
        int x = (int)((c >> (8 * d)) & 0xffull);
        total += x;
        cd[d] = (float)x;
    }
    cd[4] = (float)c4;
    cd[5] = (float)(nv - total);  // depth-5 + unreached

    const float4* e4 = (const float4*)embed;  // [6][4] float4 rows
    float4 acc = {0.f, 0.f, 0.f, 0.f};
#pragma unroll
    for (int d = 0; d <= MAXD; ++d) {
        float4 e = e4[d * 4 + q];
        acc.x += cd[d] * e.x; acc.y += cd[d] * e.y;
        acc.z += cd[d] * e.z; acc.w += cd[d] * e.w;
    }
    acc.x *= inv; acc.y *= inv; acc.z *= inv; acc.w *= inv;
    ((float4*)(out + (size_t)n * 16))[q] = acc;
}

extern "C" void kernel_launch(void* const* d_in, const int* in_sizes, int n_in,
                              void* d_out, int out_size, void* d_ws, size_t ws_size,
                              hipStream_t stream) {
    const int*   h      = (const int*)d_in[0];
    const int*   t      = (const int*)d_in[1];
    const int*   anchor = (const int*)d_in[2];
    const float* embed  = (const float*)d_in[4];
    float*       out    = (float*)d_out;

    int E = in_sizes[0];
    int A = in_sizes[2];               // 32 anchor triples -> 64 sources
    int D = in_sizes[4] / (MAXD + 1);  // 16
    int N = out_size / D;              // 50000
    int NB = (N + BN - 1) >> BSH;      // 782 buckets
    int NB1 = (E + 4 * NTH - 1) / (4 * NTH);  // 782 edge blocks (1024 edges ea)
    (void)D;

    u64* NFg       = (u64*)d_ws;
    u32* bucketCur = (u32*)(NFg + N);  // contiguous with NFg: one memset
    size_t zb = (size_t)N * 8 + (size_t)NB * 4;
    char* p  = (char*)d_ws + ((zb + 15) & ~(size_t)15);
    u64* V   = (u64*)p;
    u64* CNT = V + N;
    u64* F2  = CNT + N;
    u64* F3  = F2 + N;
    u32* srcPack = (u32*)(F3 + N);
    int* nvalid  = (int*)(srcPack + 64);
    u32* recs2   = (u32*)(srcPack + 72);   // 16B-aligned

    // zero NFg + bucketCur in one shot (403 KB)
    hipMemsetAsync(NFg, 0, zb, stream);

    build_scatter<<<NB1, NTH, 0, stream>>>(h, t, E, anchor, A,
                                           NFg, srcPack, nvalid,
                                           bucketCur, recs2);
    depth2_init<<<NB, NTH, 0, stream>>>(recs2, bucketCur, srcPack, NFg,
                                        F2, V, CNT, N);
    level3<<<NB, NTH, 0, stream>>>(recs2, bucketCur, F2, F3, V, CNT, N);
    level4_fin<<<NB, NTH, 0, stream>>>(recs2, bucketCur, F3, V, CNT,
                                       nvalid, embed, out, N);
}

// Round 4
// 343.881 us; speedup vs baseline: 1.4098x; 1.4098x over previous
//
#include <hip/hip_runtime.h>

typedef unsigned long long u64;
typedef unsigned int u32;

#define MAXD 5
#define NTH  256
#define BN   64
#define HEMPTY 0xFFFFFFFFu

// ---------------------------------------------------------------------------
// R15: edge-centric BFS. R3 proved scattered write-through stores are 88MB
// of partial-line HBM writes (384us); R2 proved software grid barriers cost
// ~65us each. So: no records, no sort, no merge. State = 5 bitmask arrays
// (V0g src bits, NF1..NF4 depth bits), 400KB each, L2-resident. Each depth
// pass streams the edge list (coalesced) and ORs the source's newly-mask
// into the target: atomicOr is monotonic, so a plain-load subset check
// skips saturated targets safely (stale copies under-report -> extra
// atomic, never a miss). frontier_k(u) = NFk[u] & ~NF_{k-1}[u] ... & ~V0[u]
// == newly_k exactly (a masked-out bit is always present one depth
// earlier, so nothing is lost). Self-loops need no guard: ~V masks them.
//
// Dispatches: memset(2MB) | d1 | d2 | d3 | d4 | finalize+matmul
// ws: V0g[N] NF1[N] NF2[N] NF3[N] NF4[N] (u64) | nvalid (int)
// ---------------------------------------------------------------------------

// depth 1: per-block src hash (proven R0/R3 pattern), push srcMask to nbrs
__global__ __launch_bounds__(NTH) void d1_push(
    const int* __restrict__ h, const int* __restrict__ t, int E,
    const int* __restrict__ anchor, int A,
    u64* __restrict__ NF1, u64* __restrict__ V0g, int* __restrict__ nvalid) {
    __shared__ u32 hsKey[128], hsBit[128];
    int tid = threadIdx.x, b = blockIdx.x;
    if (tid < 128) hsKey[tid] = HEMPTY;
    __syncthreads();

    if (tid < 64) {  // wave 0: anchor gather + shfl dedup + hash insert
        int K = 2 * A;
        int a_ = (tid < K) ? anchor[(tid < A) ? tid : (tid - A)] : 0;
        int my = (tid < K) ? ((tid < A) ? h[a_] : t[a_]) : -1;
        bool uniq = (tid < K);
        for (int j = 0; j < 64; ++j) {
            int o = __shfl(my, j, 64);
            if (j < tid && o == my) uniq = false;
        }
        u64 mask = __ballot(uniq);
        if (b == 0 && tid == 0) *nvalid = (int)__popcll(mask);
        if (uniq) {
            u32 slot = ((u32)my * 2654435761u) >> 25;
            while (atomicCAS(&hsKey[slot], HEMPTY, (u32)my) != HEMPTY)
                slot = (slot + 1) & 127u;
            hsBit[slot] = (u32)tid;
        }
        if (b == 0 && uniq) V0g[my] = 1ull << tid;  // distinct my: plain store
    }
    __syncthreads();

    auto srcMask = [&](u32 src) -> u64 {
        u32 slot = (src * 2654435761u) >> 25;
        while (true) {
            u32 k = hsKey[slot];
            if (k == src) return 1ull << hsBit[slot];
            if (k == HEMPTY) return 0ull;
            slot = (slot + 1) & 127u;
        }
    };

    int i = b * NTH + tid;
    if (i < E) {
        u32 uu = (u32)h[i], vv = (u32)t[i];
        u64 mu = srcMask(uu);
        if (mu) atomicOr(&NF1[vv], mu);
        u64 mv = srcMask(vv);
        if (mv) atomicOr(&NF1[uu], mv);
    }
}

// depth 2: frontier = NF1 & ~V0
__global__ __launch_bounds__(NTH) void d2_push(
    const int* __restrict__ h, const int* __restrict__ t, int E,
    const u64* __restrict__ V0g, const u64* __restrict__ NF1,
    u64* __restrict__ NF2) {
    int i = blockIdx.x * NTH + threadIdx.x;
    if (i >= E) return;
    u32 u = (u32)h[i], v = (u32)t[i];
    u64 fu = NF1[u] & ~V0g[u];
    u64 fv = NF1[v] & ~V0g[v];
    if (fu) { u64 cur = NF2[v]; if (fu & ~cur) atomicOr(&NF2[v], fu); }
    if (fv) { u64 cur = NF2[u]; if (fv & ~cur) atomicOr(&NF2[u], fv); }
}

// depth 3: frontier = NF2 & ~(NF1|V0)
__global__ __launch_bounds__(NTH) void d3_push(
    const int* __restrict__ h, const int* __restrict__ t, int E,
    const u64* __restrict__ V0g, const u64* __restrict__ NF1,
    const u64* __restrict__ NF2, u64* __restrict__ NF3) {
    int i = blockIdx.x * NTH + threadIdx.x;
    if (i >= E) return;
    u32 u = (u32)h[i], v = (u32)t[i];
    u64 fu = NF2[u] & ~(NF1[u] | V0g[u]);
    u64 fv = NF2[v] & ~(NF1[v] | V0g[v]);
    if (fu) { u64 cur = NF3[v]; if (fu & ~cur) atomicOr(&NF3[v], fu); }
    if (fv) { u64 cur = NF3[u]; if (fv & ~cur) atomicOr(&NF3[u], fv); }
}

// depth 4: frontier = NF3 & ~(NF2|NF1|V0)
__global__ __launch_bounds__(NTH) void d4_push(
    const int* __restrict__ h, const int* __restrict__ t, int E,
    const u64* __restrict__ V0g, const u64* __restrict__ NF1,
    const u64* __restrict__ NF2, const u64* __restrict__ NF3,
    u64* __restrict__ NF4) {
    int i = blockIdx.x * NTH + threadIdx.x;
    if (i >= E) return;
    u32 u = (u32)h[i], v = (u32)t[i];
    u64 fu = NF3[u] & ~(NF2[u] | NF1[u] | V0g[u]);
    u64 fv = NF3[v] & ~(NF2[v] | NF1[v] | V0g[v]);
    if (fu) { u64 cur = NF4[v]; if (fu & ~cur) atomicOr(&NF4[v], fu); }
    if (fv) { u64 cur = NF4[u]; if (fv & ~cur) atomicOr(&NF4[u], fv); }
}

// finalize: per-node newly_k popcounts -> counts -> matmul (quad scheme)
__global__ __launch_bounds__(NTH) void finalize(
    const u64* __restrict__ V0g, const u64* __restrict__ NF1,
    const u64* __restrict__ NF2, const u64* __restrict__ NF3,
    const u64* __restrict__ NF4, const int* __restrict__ nvalid,
    const float* __restrict__ embed, float* __restrict__ out, int N) {
    int b = blockIdx.x, tid = threadIdx.x;
    int nl = tid >> 2, q = tid & 3;   // 64 nodes x 4 float4 quads (D=16)
    int n = b * BN + nl;
    if (n >= N) return;
    u64 s  = V0g[n];
    u64 n1 = NF1[n] & ~s;          u64 v1 = s  | n1;
    u64 n2 = NF2[n] & ~v1;         u64 v2 = v1 | n2;
    u64 n3 = NF3[n] & ~v2;         u64 v3 = v2 | n3;
    u64 n4 = NF4[n] & ~v3;
    int nv = *nvalid;
    float inv = 1.0f / (float)(nv > 0 ? nv : 1);
    int c0 = s ? 1 : 0;
    int c1 = __popcll(n1), c2 = __popcll(n2);
    int c3 = __popcll(n3), c4 = __popcll(n4);
    float cd[MAXD + 1];
    cd[0] = (float)c0; cd[1] = (float)c1; cd[2] = (float)c2;
    cd[3] = (float)c3; cd[4] = (float)c4;
    cd[5] = (float)(nv - (c0 + c1 + c2 + c3 + c4));  // depth-5 + unreached

    const float4* e4 = (const float4*)embed;  // [6][4] float4 rows
    float4 acc = {0.f, 0.f, 0.f, 0.f};
#pragma unroll
    for (int d = 0; d <= MAXD; ++d) {
        float4 e = e4[d * 4 + q];
        acc.x += cd[d] * e.x; acc.y += cd[d] * e.y;
        acc.z += cd[d] * e.z; acc.w += cd[d] * e.w;
    }
    acc.x *= inv; acc.y *= inv; acc.z *= inv; acc.w *= inv;
    ((float4*)(out + (size_t)n * 16))[q] = acc;
}

extern "C" void kernel_launch(void* const* d_in, const int* in_sizes, int n_in,
                              void* d_out, int out_size, void* d_ws, size_t ws_size,
                              hipStream_t stream) {
    const int*   h      = (const int*)d_in[0];
    const int*   t      = (const int*)d_in[1];
    const int*   anchor = (const int*)d_in[2];
    const float* embed  = (const float*)d_in[4];
    float*       out    = (float*)d_out;

    int E = in_sizes[0];
    int A = in_sizes[2];               // 32 anchor triples -> 64 sources
    int D = in_sizes[4] / (MAXD + 1);  // 16
    int N = out_size / D;              // 50000
    int NBe = (E + NTH - 1) / NTH;     // 3125 edge blocks (1 edge/thread)
    int NBn = (N + BN - 1) / BN;       // 782 node blocks
    (void)D;

    u64* V0g = (u64*)d_ws;
    u64* NF1 = V0g + N;
    u64* NF2 = NF1 + N;
    u64* NF3 = NF2 + N;
    u64* NF4 = NF3 + N;
    int* nvalid = (int*)(NF4 + N);

    // zero all five mask arrays in one shot (2 MB)
    hipMemsetAsync(V0g, 0, (size_t)N * 5 * 8, stream);

    d1_push<<<NBe, NTH, 0, stream>>>(h, t, E, anchor, A, NF1, V0g, nvalid);
    d2_push<<<NBe, NTH, 0, stream>>>(h, t, E, V0g, NF1, NF2);
    d3_push<<<NBe, NTH, 0, stream>>>(h, t, E, V0g, NF1, NF2, NF3);
    d4_push<<<NBe, NTH, 0, stream>>>(h, t, E, V0g, NF1, NF2, NF3, NF4);
    finalize<<<NBn, NTH, 0, stream>>>(V0g, NF1, NF2, NF3, NF4,
                                      nvalid, embed, out, N);
}

// Round 5
// 235.303 us; speedup vs baseline: 2.0603x; 1.4614x over previous
//
#include <hip/hip_runtime.h>

typedef unsigned long long u64;
typedef unsigned int u32;

#define MAXD 5
#define NTH  256
#define BN   64
#define EPT  4            // edges per thread
#define HEMPTY 0xFFFFFFFFu

// ---------------------------------------------------------------------------
// R16: edge-centric BFS, fixed. R4's d3/d4 cost came from (a) skip checks
// that only tested the current depth's array -> atomicOr on ~every edge
// (3.2M device atomics in d4), and (b) masks spread over 5 arrays -> up to
// 5 lines per endpoint. Fix: one 64B line per node M[n][8] =
// {V0,NF1,NF2,NF3,NF4,pad3} (3.2MB, L2-resident), loaded as ulonglong2
// pairs; the full visited set of the TARGET is then in registers for free,
// so we only atomicOr when the push adds a bit not visited at ANY depth
// <= k. Monotone bits => stale reads only cause extra atomics, never
// missed ones. Edge list is read nontemporally (streaming; keep mask
// lines in L2). 4 edges/thread for ILP.
//
// Dispatches: memset(3.2MB) | d1 | d2 | d3 | d4 | finalize+matmul
// ws: M[N][8] (u64) | nvalid (int)
// ---------------------------------------------------------------------------

__device__ __forceinline__ int ntload(const int* p) {
    return __builtin_nontemporal_load(p);
}

// depth 1: per-block src hash (proven pattern), push srcMask to neighbors
__global__ __launch_bounds__(NTH) void d1_push(
    const int* __restrict__ h, const int* __restrict__ t, int E,
    const int* __restrict__ anchor, int A,
    u64* __restrict__ M, int* __restrict__ nvalid) {
    __shared__ u32 hsKey[128], hsBit[128];
    int tid = threadIdx.x, b = blockIdx.x;
    if (tid < 128) hsKey[tid] = HEMPTY;
    __syncthreads();

    if (tid < 64) {  // wave 0: anchor gather + shfl dedup + hash insert
        int K = 2 * A;
        int a_ = (tid < K) ? anchor[(tid < A) ? tid : (tid - A)] : 0;
        int my = (tid < K) ? ((tid < A) ? h[a_] : t[a_]) : -1;
        bool uniq = (tid < K);
        for (int j = 0; j < 64; ++j) {
            int o = __shfl(my, j, 64);
            if (j < tid && o == my) uniq = false;
        }
        u64 mask = __ballot(uniq);
        if (b == 0 && tid == 0) *nvalid = (int)__popcll(mask);
        if (uniq) {
            u32 slot = ((u32)my * 2654435761u) >> 25;
            while (atomicCAS(&hsKey[slot], HEMPTY, (u32)my) != HEMPTY)
                slot = (slot + 1) & 127u;
            hsBit[slot] = (u32)tid;
        }
        if (b == 0 && uniq) M[(size_t)my * 8] = 1ull << tid;  // V0: plain store
    }
    __syncthreads();

    auto srcMask = [&](u32 src) -> u64 {
        u32 slot = (src * 2654435761u) >> 25;
        while (true) {
            u32 k = hsKey[slot];
            if (k == src) return 1ull << hsBit[slot];
            if (k == HEMPTY) return 0ull;
            slot = (slot + 1) & 127u;
        }
    };

    int base = b * (EPT * NTH);
#pragma unroll
    for (int k = 0; k < EPT; ++k) {
        int i = base + k * NTH + tid;
        if (i < E) {
            u32 uu = (u32)ntload(h + i), vv = (u32)ntload(t + i);
            u64 mu = srcMask(uu);
            if (mu) atomicOr(&M[(size_t)vv * 8 + 1], mu);
            u64 mv = srcMask(vv);
            if (mv) atomicOr(&M[(size_t)uu * 8 + 1], mv);
        }
    }
}

// depth 2: frontier = NF1 & ~V0; skip if no bit new vs target's {V0,NF1,NF2}
__global__ __launch_bounds__(NTH) void d2_push(
    const int* __restrict__ h, const int* __restrict__ t, int E,
    u64* __restrict__ M) {
    const ulonglong2* M2 = (const ulonglong2*)M;
    int tid = threadIdx.x, b = blockIdx.x;
    int base = b * (EPT * NTH);
#pragma unroll
    for (int k = 0; k < EPT; ++k) {
        int i = base + k * NTH + tid;
        if (i < E) {
            u32 u = (u32)ntload(h + i), v = (u32)ntload(t + i);
            ulonglong2 au = M2[(size_t)u * 4];      // {V0,NF1}
            ulonglong2 av = M2[(size_t)v * 4];
            u64 fu = au.y & ~au.x;
            u64 fv = av.y & ~av.x;
            if (fu | fv) {
                u64 n2u = M[(size_t)u * 8 + 2];
                u64 n2v = M[(size_t)v * 8 + 2];
                if (fu & ~(av.x | av.y | n2v))
                    atomicOr(&M[(size_t)v * 8 + 2], fu);
                if (fv & ~(au.x | au.y | n2u))
                    atomicOr(&M[(size_t)u * 8 + 2], fv);
            }
        }
    }
}

// depth 3: frontier = NF2 & ~(NF1|V0); skip vs target's {V0,NF1,NF2,NF3}
__global__ __launch_bounds__(NTH) void d3_push(
    const int* __restrict__ h, const int* __restrict__ t, int E,
    u64* __restrict__ M) {
    const ulonglong2* M2 = (const ulonglong2*)M;
    int tid = threadIdx.x, b = blockIdx.x;
    int base = b * (EPT * NTH);
#pragma unroll
    for (int k = 0; k < EPT; ++k) {
        int i = base + k * NTH + tid;
        if (i < E) {
            u32 u = (u32)ntload(h + i), v = (u32)ntload(t + i);
            ulonglong2 au = M2[(size_t)u * 4];      // {V0,NF1}
            ulonglong2 bu = M2[(size_t)u * 4 + 1];  // {NF2,NF3}
            ulonglong2 av = M2[(size_t)v * 4];
            ulonglong2 bv = M2[(size_t)v * 4 + 1];
            u64 fu = bu.x & ~(au.x | au.y);
            u64 fv = bv.x & ~(av.x | av.y);
            if (fu & ~(av.x | av.y | bv.x | bv.y))
                atomicOr(&M[(size_t)v * 8 + 3], fu);
            if (fv & ~(au.x | au.y | bu.x | bu.y))
                atomicOr(&M[(size_t)u * 8 + 3], fv);
        }
    }
}

// depth 4: frontier = NF3 & ~(NF2|NF1|V0); skip vs {V0..NF4}
__global__ __launch_bounds__(NTH) void d4_push(
    const int* __restrict__ h, const int* __restrict__ t, int E,
    u64* __restrict__ M) {
    const ulonglong2* M2 = (const ulonglong2*)M;
    int tid = threadIdx.x, b = blockIdx.x;
    int base = b * (EPT * NTH);
#pragma unroll
    for (int k = 0; k < EPT; ++k) {
        int i = base + k * NTH + tid;
        if (i < E) {
            u32 u = (u32)ntload(h + i), v = (u32)ntload(t + i);
            ulonglong2 au = M2[(size_t)u * 4];      // {V0,NF1}
            ulonglong2 bu = M2[(size_t)u * 4 + 1];  // {NF2,NF3}
            ulonglong2 av = M2[(size_t)v * 4];
            ulonglong2 bv = M2[(size_t)v * 4 + 1];
            u64 fu = bu.y & ~(bu.x | au.y | au.x);
            u64 fv = bv.y & ~(bv.x | av.y | av.x);
            if (fu | fv) {
                u64 n4u = M[(size_t)u * 8 + 4];
                u64 n4v = M[(size_t)v * 8 + 4];
                if (fu & ~(av.x | av.y | bv.x | bv.y | n4v))
                    atomicOr(&M[(size_t)v * 8 + 4], fu);
                if (fv & ~(au.x | au.y | bu.x | bu.y | n4u))
                    atomicOr(&M[(size_t)u * 8 + 4], fv);
            }
        }
    }
}

// finalize: per-node newly_k popcounts -> counts -> matmul (quad scheme)
__global__ __launch_bounds__(NTH) void finalize(
    const u64* __restrict__ M, const int* __restrict__ nvalid,
    const float* __restrict__ embed, float* __restrict__ out, int N) {
    int b = blockIdx.x, tid = threadIdx.x;
    int nl = tid >> 2, q = tid & 3;   // 64 nodes x 4 float4 quads (D=16)
    int n = b * BN + nl;
    if (n >= N) return;
    const ulonglong2* M2 = (const ulonglong2*)M;
    ulonglong2 a = M2[(size_t)n * 4];      // {V0,NF1}
    ulonglong2 c2 = M2[(size_t)n * 4 + 1]; // {NF2,NF3}
    u64 nf4 = M[(size_t)n * 8 + 4];
    u64 s  = a.x;
    u64 n1 = a.y  & ~s;            u64 v1 = s  | n1;
    u64 n2 = c2.x & ~v1;           u64 v2 = v1 | n2;
    u64 n3 = c2.y & ~v2;           u64 v3 = v2 | n3;
    u64 n4 = nf4  & ~v3;
    int nv = *nvalid;
    float inv = 1.0f / (float)(nv > 0 ? nv : 1);
    int c0 = s ? 1 : 0;
    int cc1 = __popcll(n1), cc2 = __popcll(n2);
    int cc3 = __popcll(n3), cc4 = __popcll(n4);
    float cd[MAXD + 1];
    cd[0] = (float)c0; cd[1] = (float)cc1; cd[2] = (float)cc2;
    cd[3] = (float)cc3; cd[4] = (float)cc4;
    cd[5] = (float)(nv - (c0 + cc1 + cc2 + cc3 + cc4));  // depth-5 + unreached

    const float4* e4 = (const float4*)embed;  // [6][4] float4 rows
    float4 acc = {0.f, 0.f, 0.f, 0.f};
#pragma unroll
    for (int d = 0; d <= MAXD; ++d) {
        float4 e = e4[d * 4 + q];
        acc.x += cd[d] * e.x; acc.y += cd[d] * e.y;
        acc.z += cd[d] * e.z; acc.w += cd[d] * e.w;
    }
    acc.x *= inv; acc.y *= inv; acc.z *= inv; acc.w *= inv;
    ((float4*)(out + (size_t)n * 16))[q] = acc;
}

extern "C" void kernel_launch(void* const* d_in, const int* in_sizes, int n_in,
                              void* d_out, int out_size, void* d_ws, size_t ws_size,
                              hipStream_t stream) {
    const int*   h      = (const int*)d_in[0];
    const int*   t      = (const int*)d_in[1];
    const int*   anchor = (const int*)d_in[2];
    const float* embed  = (const float*)d_in[4];
    float*       out    = (float*)d_out;

    int E = in_sizes[0];
    int A = in_sizes[2];               // 32 anchor triples -> 64 sources
    int D = in_sizes[4] / (MAXD + 1);  // 16
    int N = out_size / D;              // 50000
    int NBe = (E + EPT * NTH - 1) / (EPT * NTH);  // 782 edge blocks
    int NBn = (N + BN - 1) / BN;                  // 782 node blocks
    (void)D;

    u64* M = (u64*)d_ws;               // [N][8] u64, 64B line per node
    int* nvalid = (int*)(M + (size_t)N * 8);

    // zero the mask lines (3.2 MB)
    hipMemsetAsync(M, 0, (size_t)N * 8 * 8, stream);

    d1_push<<<NBe, NTH, 0, stream>>>(h, t, E, anchor, A, M, nvalid);
    d2_push<<<NBe, NTH, 0, stream>>>(h, t, E, M);
    d3_push<<<NBe, NTH, 0, stream>>>(h, t, E, M);
    d4_push<<<NBe, NTH, 0, stream>>>(h, t, E, M);
    finalize<<<NBn, NTH, 0, stream>>>(M, nvalid, embed, out, N);
}

// Round 6
// 152.595 us; speedup vs baseline: 3.1770x; 1.5420x over previous
//
#include <hip/hip_runtime.h>

typedef unsigned long long u64;
typedef unsigned int u32;

#define MAXD 5
#define NTH  256
#define BN   64
#define BIN_SH 9
#define BIN_NODES 512
#define SL   16          // slice blocks per bin
#define CAPB 24576       // records per bin capacity (mean ~12.5K, sd ~160)
#define HEMPTY 0xFFFFFFFFu

// ---------------------------------------------------------------------------
// R17: pull-based BFS with binned adjacency. R5 proved push+device-atomicOr
// structurally evicts its own state from L2 (93MB refetch in d3): every
// atomic bypasses/invalidates L2. Pull fixes it: records grouped by target
// bin (512 nodes); depth passes accumulate in LDS (free atomics), write
// partial masks with plain coalesced stores into 16 P-slabs; frontier
// array is READ-ONLY during a pass -> L2-resident on all XCDs. A tiny
// node-parallel combine ORs the 16 partials. No device atomics in any
// depth pass. The bin build (sortA) is one LDS-staged pass writing
// contiguous runs (~42 recs avg -> near-full-line stores) + 38K cursor
// atomics -- the cheap version of R0's 70us sort/merge, without R3's
// write-through disaster.
//
// Dispatches: memset(401KB) | anchors | sortA | 4x(pull+combine) | final
// ws: V0[N] (u64) binCur[128] nvalid (zeroed) | Vis NF1 NF2 NF3 [N] |
//     P[SL][NP] | binBuf[NBIN*CAPB] (u32)
// ---------------------------------------------------------------------------

// unique anchor sources -> V0 bit per source, nvalid
__global__ void anchors_k(const int* __restrict__ h, const int* __restrict__ t,
                          const int* __restrict__ anchor, int A,
                          u64* __restrict__ V0, int* __restrict__ nvalid) {
    int tid = threadIdx.x;
    int K = 2 * A;
    int a_ = (tid < K) ? anchor[(tid < A) ? tid : (tid - A)] : 0;
    int my = (tid < K) ? ((tid < A) ? h[a_] : t[a_]) : -1;
    bool uniq = (tid < K);
    for (int j = 0; j < 64; ++j) {
        int o = __shfl(my, j, 64);
        if (j < tid && o == my) uniq = false;
    }
    u64 mask = __ballot(uniq);
    if (tid == 0) *nvalid = (int)__popcll(mask);
    if (uniq) V0[my] = 1ull << tid;   // distinct my per lane: plain store
}

// bin 1.6M directed records by target's 512-node bin; contiguous run writes
__global__ __launch_bounds__(NTH) void sortA(
    const int* __restrict__ h, const int* __restrict__ t, int E, int NBIN,
    u32* __restrict__ binCur, u32* __restrict__ binBuf) {
    __shared__ u32 hist[128], base[128];
    __shared__ u32 offs[129];
    __shared__ u32 buf[4096];
    int tid = threadIdx.x, b = blockIdx.x;
    int e0 = b * 4 * NTH * 2 / 2;     // 1024 edges? no: 2048 edges/block
    e0 = b * 2048;
    u32 eu[8], ev[8];
#pragma unroll
    for (int k = 0; k < 8; ++k) {
        int i = e0 + k * NTH + tid;
        if (i < E) {
            eu[k] = (u32)__builtin_nontemporal_load(h + i);
            ev[k] = (u32)__builtin_nontemporal_load(t + i);
        } else { eu[k] = HEMPTY; ev[k] = HEMPTY; }
    }
    for (int i = tid; i < NBIN; i += NTH) hist[i] = 0u;
    __syncthreads();
#pragma unroll
    for (int k = 0; k < 8; ++k) {
        if (eu[k] != HEMPTY) {
            atomicAdd(&hist[ev[k] >> BIN_SH], 1u);
            atomicAdd(&hist[eu[k] >> BIN_SH], 1u);
        }
    }
    __syncthreads();
    if (tid == 0) {                    // serial scan: NBIN<=128, ~cheap
        u32 s = 0;
        for (int j = 0; j < NBIN; ++j) { offs[j] = s; s += hist[j]; }
        offs[NBIN] = s;
    }
    __syncthreads();
    if (tid < NBIN) {
        u32 c = offs[tid + 1] - offs[tid];
        base[tid] = c ? atomicAdd(&binCur[tid], c) : 0u;
        hist[tid] = 0u;                // reuse as placement cursor
    }
    __syncthreads();
#pragma unroll
    for (int k = 0; k < 8; ++k) {
        if (eu[k] != HEMPTY) {
            u32 b1 = ev[k] >> BIN_SH;
            buf[offs[b1] + atomicAdd(&hist[b1], 1u)] =
                (eu[k] << BIN_SH) | (ev[k] & (BIN_NODES - 1));
            u32 b2 = eu[k] >> BIN_SH;
            buf[offs[b2] + atomicAdd(&hist[b2], 1u)] =
                (ev[k] << BIN_SH) | (eu[k] & (BIN_NODES - 1));
        }
    }
    __syncthreads();
    u32 tot = offs[NBIN];
    for (u32 i = tid; i < tot; i += NTH) {
        int c = 0;                     // largest c with offs[c] <= i
#pragma unroll
        for (int step = 64; step >= 1; step >>= 1)
            if (c + step <= NBIN - 1 && offs[c + step] <= i) c += step;
        u32 pos = base[c] + (i - offs[c]);
        if (pos < CAPB) binBuf[(size_t)c * CAPB + pos] = buf[i];
    }
}

// one depth pass: LDS-accumulate bin partials from Fin gathers (read-only)
__global__ __launch_bounds__(NTH) void pull_k(
    const u32* __restrict__ binBuf, const u32* __restrict__ binCur,
    const u64* __restrict__ Fin, u64* __restrict__ P, int NP) {
    __shared__ u64 NF[BIN_NODES];
    int bin = blockIdx.x >> 4, sl = blockIdx.x & (SL - 1);
    int tid = threadIdx.x;
    for (int j = tid; j < BIN_NODES; j += NTH) NF[j] = 0ull;
    __syncthreads();
    u32 cnt = min(binCur[bin], (u32)CAPB);
    u32 per = (cnt + SL - 1) / SL;
    u32 r0 = min((u32)sl * per, cnt), r1 = min(r0 + per, cnt);
    const u32* rb = binBuf + (size_t)bin * CAPB;
    u32 r = r0 + tid;
    for (; r + 3u * NTH < r1; r += 4u * NTH) {
        u32 a0 = __builtin_nontemporal_load(rb + r);
        u32 a1 = __builtin_nontemporal_load(rb + r + NTH);
        u32 a2 = __builtin_nontemporal_load(rb + r + 2 * NTH);
        u32 a3 = __builtin_nontemporal_load(rb + r + 3 * NTH);
        u64 f0 = Fin[a0 >> BIN_SH], f1 = Fin[a1 >> BIN_SH];
        u64 f2 = Fin[a2 >> BIN_SH], f3 = Fin[a3 >> BIN_SH];
        if (f0) atomicOr(&NF[a0 & (BIN_NODES - 1)], f0);
        if (f1) atomicOr(&NF[a1 & (BIN_NODES - 1)], f1);
        if (f2) atomicOr(&NF[a2 & (BIN_NODES - 1)], f2);
        if (f3) atomicOr(&NF[a3 & (BIN_NODES - 1)], f3);
    }
    for (; r < r1; r += NTH) {
        u32 a0 = __builtin_nontemporal_load(rb + r);
        u64 f0 = Fin[a0 >> BIN_SH];
        if (f0) atomicOr(&NF[a0 & (BIN_NODES - 1)], f0);
    }
    __syncthreads();
    u64* Pd = P + (size_t)sl * NP + ((size_t)bin << BIN_SH);
    for (int j = tid; j < BIN_NODES; j += NTH) Pd[j] = NF[j];  // plain stores
}

// combine after depth 1: NF1 = raw & ~V0; Vis = V0 | NF1
__global__ __launch_bounds__(NTH) void combine1_k(
    const u64* __restrict__ P, int NP, const u64* __restrict__ V0,
    u64* __restrict__ NF1, u64* __restrict__ Vis, int N) {
    int n = blockIdx.x * NTH + threadIdx.x;
    if (n >= N) return;
    u64 raw = 0ull;
#pragma unroll
    for (int s = 0; s < SL; ++s) raw |= P[(size_t)s * NP + n];
    u64 v0 = V0[n];
    u64 nw = raw & ~v0;
    NF1[n] = nw;
    Vis[n] = v0 | nw;
}

// combine after depth k (2,3): NFk = raw & ~Vis; Vis |= NFk
__global__ __launch_bounds__(NTH) void combine_k(
    const u64* __restrict__ P, int NP,
    u64* __restrict__ NFk, u64* __restrict__ Vis, int N) {
    int n = blockIdx.x * NTH + threadIdx.x;
    if (n >= N) return;
    u64 raw = 0ull;
#pragma unroll
    for (int s = 0; s < SL; ++s) raw |= P[(size_t)s * NP + n];
    u64 vis = Vis[n];
    u64 nw = raw & ~vis;
    NFk[n] = nw;
    Vis[n] = vis | nw;
}

// final: combine depth-4 partials + counts + matmul (quad scheme, D=16)
__global__ __launch_bounds__(NTH) void final_k(
    const u64* __restrict__ P, int NP, const u64* __restrict__ V0,
    const u64* __restrict__ NF1, const u64* __restrict__ NF2,
    const u64* __restrict__ NF3, const u64* __restrict__ Vis,
    const int* __restrict__ nvalid, const float* __restrict__ embed,
    float* __restrict__ out, int N) {
    __shared__ float cds[BN][8];      // 6 used, padded
    int b = blockIdx.x, tid = threadIdx.x;
    int nv = *nvalid;
    if (tid < BN) {
        int n = b * BN + tid;
        if (n < N) {
            u64 raw = 0ull;
#pragma unroll
            for (int s = 0; s < SL; ++s) raw |= P[(size_t)s * NP + n];
            u64 n4 = raw & ~Vis[n];
            int c0 = V0[n] ? 1 : 0;
            int c1 = __popcll(NF1[n]), c2 = __popcll(NF2[n]);
            int c3 = __popcll(NF3[n]), c4 = __popcll(n4);
            cds[tid][0] = (float)c0; cds[tid][1] = (float)c1;
            cds[tid][2] = (float)c2; cds[tid][3] = (float)c3;
            cds[tid][4] = (float)c4;
            cds[tid][5] = (float)(nv - (c0 + c1 + c2 + c3 + c4));
        }
    }
    __syncthreads();
    int nl = tid >> 2, q = tid & 3;
    int n = b * BN + nl;
    if (n >= N) return;
    float inv = 1.0f / (float)(nv > 0 ? nv : 1);
    const float4* e4 = (const float4*)embed;   // [6][4] float4 rows
    float4 acc = {0.f, 0.f, 0.f, 0.f};
#pragma unroll
    for (int d = 0; d <= MAXD; ++d) {
        float cd = cds[nl][d];
        float4 e = e4[d * 4 + q];
        acc.x += cd * e.x; acc.y += cd * e.y;
        acc.z += cd * e.z; acc.w += cd * e.w;
    }
    acc.x *= inv; acc.y *= inv; acc.z *= inv; acc.w *= inv;
    ((float4*)(out + (size_t)n * 16))[q] = acc;
}

extern "C" void kernel_launch(void* const* d_in, const int* in_sizes, int n_in,
                              void* d_out, int out_size, void* d_ws, size_t ws_size,
                              hipStream_t stream) {
    const int*   h      = (const int*)d_in[0];
    const int*   t      = (const int*)d_in[1];
    const int*   anchor = (const int*)d_in[2];
    const float* embed  = (const float*)d_in[4];
    float*       out    = (float*)d_out;

    int E = in_sizes[0];
    int A = in_sizes[2];                    // 32 anchor triples -> 64 sources
    int D = in_sizes[4] / (MAXD + 1);       // 16
    int N = out_size / D;                   // 50000
    int NBIN = (N + BIN_NODES - 1) >> BIN_SH;   // 98
    int NP   = NBIN << BIN_SH;                  // 50176
    int NBs  = (E + 2047) / 2048;               // 391 sortA blocks
    int NBc  = (N + NTH - 1) / NTH;             // 196 combine blocks
    int NBf  = (N + BN - 1) / BN;               // 782 final blocks
    (void)D;

    // zeroed region first: V0 | binCur[128] | nvalid | pad
    u64* V0     = (u64*)d_ws;
    u32* binCur = (u32*)(V0 + N);
    int* nvalid = (int*)(binCur + 128);
    u64* Vis    = (u64*)((char*)d_ws + (((size_t)N * 8 + 128 * 4 + 16 + 15) & ~(size_t)15));
    u64* NF1    = Vis + N;
    u64* NF2    = NF1 + N;
    u64* NF3    = NF2 + N;
    u64* P      = NF3 + N;                  // [SL][NP]
    u32* binBuf = (u32*)(P + (size_t)SL * NP);  // [NBIN][CAPB]

    hipMemsetAsync(V0, 0, (size_t)N * 8 + 128 * 4 + 16, stream);

    anchors_k<<<1, 64, 0, stream>>>(h, t, anchor, A, V0, nvalid);
    sortA<<<NBs, NTH, 0, stream>>>(h, t, E, NBIN, binCur, binBuf);

    pull_k<<<NBIN * SL, NTH, 0, stream>>>(binBuf, binCur, V0, P, NP);
    combine1_k<<<NBc, NTH, 0, stream>>>(P, NP, V0, NF1, Vis, N);

    pull_k<<<NBIN * SL, NTH, 0, stream>>>(binBuf, binCur, NF1, P, NP);
    combine_k<<<NBc, NTH, 0, stream>>>(P, NP, NF2, Vis, N);

    pull_k<<<NBIN * SL, NTH, 0, stream>>>(binBuf, binCur, NF2, P, NP);
    combine_k<<<NBc, NTH, 0, stream>>>(P, NP, NF3, Vis, N);

    pull_k<<<NBIN * SL, NTH, 0, stream>>>(binBuf, binCur, NF3, P, NP);
    final_k<<<NBf, NTH, 0, stream>>>(P, NP, V0, NF1, NF2, NF3, Vis,
                                     nvalid, embed, out, N);
}

// Round 7
// 147.827 us; speedup vs baseline: 3.2795x; 1.0323x over previous
//
#include <hip/hip_runtime.h>

typedef unsigned long long u64;
typedef unsigned int u32;

#define MAXD 5
#define NTH  256
#define BIN_SH 7
#define BIN_NODES 128
#define MAXBIN 512
#define CAPB 5120       // records per 128-node bin (mean 4096, sd 64, +16s)
#define EPB  2048       // edges per sortA block
#define HEMPTY 0xFFFFFFFFu

// ---------------------------------------------------------------------------
// R18: pull-BFS with SL=1 bin ownership. R6 (SL=16) worked but paid a P-slab
// round trip (6.4MB write + read per depth) + 4 combine dispatches + 11
// launch gaps. With 128-node bins (NBIN=391 blocks) each bin is owned by
// ONE block: newly-mask lives in LDS, ~Vis / Vis-update / CNT-pack / next
// frontier are plain bin-owned stores. No partials, no combines, no device
// atomics in any depth pass (R5 lesson). Anchor set is recomputed per
// block via shfl-dedup -> no V0 array, and pull kernels fully overwrite
// their nodes' state -> only binCur (2KB) needs zeroing. Depth 4 fuses the
// matmul. Frontier arrays ping-pong Fa/Fb, read-only during a pass ->
// L2-resident (no atomic invalidation, R5 lesson).
//
// Dispatches: memset(2KB) | sortA | pull1 | pull2 | pull3 | pull4+final
// ws: binCur[512] | Vis Fa Fb CNT [N] (u64) | binBuf[NBIN*CAPB] (u32)
// ---------------------------------------------------------------------------

// bin 1.6M directed records by target's 128-node bin; contiguous run writes
__global__ __launch_bounds__(NTH) void sortA(
    const int* __restrict__ h, const int* __restrict__ t, int E, int NBIN,
    u32* __restrict__ binCur, u32* __restrict__ binBuf) {
    __shared__ u32 hist[MAXBIN], base[MAXBIN];
    __shared__ u32 offs[MAXBIN + 1];
    __shared__ u32 waveSum[4];
    __shared__ u32 buf[2 * EPB];
    int tid = threadIdx.x, b = blockIdx.x;
    int lane = tid & 63, w = tid >> 6;
    int e0 = b * EPB;
    u32 eu[8], ev[8];
#pragma unroll
    for (int k = 0; k < 8; ++k) {
        int i = e0 + k * NTH + tid;
        if (i < E) {
            eu[k] = (u32)__builtin_nontemporal_load(h + i);
            ev[k] = (u32)__builtin_nontemporal_load(t + i);
        } else { eu[k] = HEMPTY; ev[k] = HEMPTY; }
    }
    for (int i = tid; i < NBIN; i += NTH) hist[i] = 0u;
    __syncthreads();
#pragma unroll
    for (int k = 0; k < 8; ++k) {
        if (eu[k] != HEMPTY) {
            atomicAdd(&hist[ev[k] >> BIN_SH], 1u);
            atomicAdd(&hist[eu[k] >> BIN_SH], 1u);
        }
    }
    __syncthreads();
    // hierarchical exclusive scan, 2 entries/thread (proven pattern)
    {
        u32 i0 = (u32)tid * 2;
        u32 a0 = (i0 < (u32)NBIN) ? hist[i0] : 0u;
        u32 a1 = (i0 + 1 < (u32)NBIN) ? hist[i0 + 1] : 0u;
        u32 sum = a0 + a1;
        u32 p = sum;
#pragma unroll
        for (int d = 1; d < 64; d <<= 1) {
            u32 x = (u32)__shfl_up((int)p, d, 64);
            if (lane >= d) p += x;
        }
        u32 excl = p - sum;
        if (lane == 63) waveSum[w] = p;
        __syncthreads();
        u32 woff = 0;
        for (int k = 0; k < w; ++k) woff += waveSum[k];
        u32 o0 = woff + excl;
        if (i0 < (u32)NBIN) offs[i0] = o0;
        if (i0 + 1 < (u32)NBIN) offs[i0 + 1] = o0 + a0;
        if (tid == NTH - 1) offs[NBIN] = o0 + a0 + a1;  // = total (tail aa=0)
    }
    __syncthreads();
    for (int j = tid; j < NBIN; j += NTH) {
        u32 c = offs[j + 1] - offs[j];
        base[j] = c ? atomicAdd(&binCur[j], c) : 0u;
        hist[j] = 0u;                  // reuse as placement cursor
    }
    __syncthreads();
#pragma unroll
    for (int k = 0; k < 8; ++k) {
        if (eu[k] != HEMPTY) {
            u32 b1 = ev[k] >> BIN_SH;
            buf[offs[b1] + atomicAdd(&hist[b1], 1u)] =
                (eu[k] << BIN_SH) | (ev[k] & (BIN_NODES - 1));
            u32 b2 = eu[k] >> BIN_SH;
            buf[offs[b2] + atomicAdd(&hist[b2], 1u)] =
                (ev[k] << BIN_SH) | (eu[k] & (BIN_NODES - 1));
        }
    }
    __syncthreads();
    u32 tot = offs[NBIN];
    for (u32 i = tid; i < tot; i += NTH) {
        int c = 0;                     // largest c with offs[c] <= i
#pragma unroll
        for (int step = 256; step >= 1; step >>= 1)
            if (c + step <= NBIN - 1 && offs[c + step] <= i) c += step;
        u32 pos = base[c] + (i - offs[c]);
        if (pos < CAPB) binBuf[(size_t)c * CAPB + pos] = buf[i];  // L2-merged
    }
}

// depth 1: LDS anchor hash (no V0 array); init Vis/F1/CNT for own bin
__global__ __launch_bounds__(NTH) void pull1(
    const u32* __restrict__ binBuf, const u32* __restrict__ binCur,
    const int* __restrict__ h, const int* __restrict__ t,
    const int* __restrict__ anchor, int A,
    u64* __restrict__ F1, u64* __restrict__ Vis, u64* __restrict__ CNT,
    int N) {
    __shared__ u64 NF[BIN_NODES];
    __shared__ u32 hsKey[128], hsBit[128];
    int tid = threadIdx.x, bin = blockIdx.x;
    if (tid < 128) { NF[tid & (BIN_NODES - 1)] = 0ull; hsKey[tid] = HEMPTY; }
    __syncthreads();
    if (tid < 64) {   // wave 0: anchor gather + shfl dedup + hash insert
        int K = 2 * A;
        int a_ = (tid < K) ? anchor[(tid < A) ? tid : (tid - A)] : 0;
        int my = (tid < K) ? ((tid < A) ? h[a_] : t[a_]) : -1;
        bool uniq = (tid < K);
        for (int j = 0; j < 64; ++j) {
            int o = __shfl(my, j, 64);
            if (j < tid && o == my) uniq = false;
        }
        if (uniq) {
            u32 slot = ((u32)my * 2654435761u) >> 25;
            while (atomicCAS(&hsKey[slot], HEMPTY, (u32)my) != HEMPTY)
                slot = (slot + 1) & 127u;
            hsBit[slot] = (u32)tid;
        }
    }
    __syncthreads();
    auto srcMask = [&](u32 src) -> u64 {
        u32 slot = (src * 2654435761u) >> 25;
        while (true) {
            u32 k = hsKey[slot];
            if (k == src) return 1ull << hsBit[slot];
            if (k == HEMPTY) return 0ull;
            slot = (slot + 1) & 127u;
        }
    };
    u32 cnt = min(binCur[bin], (u32)CAPB);
    const u32* rb = binBuf + (size_t)bin * CAPB;
    const uint4* rb4 = (const uint4*)rb;
    u32 n4 = cnt >> 2;
    for (u32 i = tid; i < n4; i += NTH) {
        uint4 rr = rb4[i];
        u64 f0 = srcMask(rr.x >> BIN_SH), f1 = srcMask(rr.y >> BIN_SH);
        u64 f2 = srcMask(rr.z >> BIN_SH), f3 = srcMask(rr.w >> BIN_SH);
        if (f0) atomicOr(&NF[rr.x & (BIN_NODES - 1)], f0);
        if (f1) atomicOr(&NF[rr.y & (BIN_NODES - 1)], f1);
        if (f2) atomicOr(&NF[rr.z & (BIN_NODES - 1)], f2);
        if (f3) atomicOr(&NF[rr.w & (BIN_NODES - 1)], f3);
    }
    for (u32 r = (n4 << 2) + tid; r < cnt; r += NTH) {
        u32 a0 = rb[r];
        u64 f0 = srcMask(a0 >> BIN_SH);
        if (f0) atomicOr(&NF[a0 & (BIN_NODES - 1)], f0);
    }
    __syncthreads();
    if (tid < BIN_NODES) {
        int n = bin * BIN_NODES + tid;
        if (n < N) {
            u64 srcbit = srcMask((u32)n);
            u64 nw = NF[tid] & ~srcbit;
            F1[n] = nw;
            Vis[n] = srcbit | nw;
            CNT[n] = (srcbit ? 1ull : 0ull) | ((u64)__popcll(nw) << 8);
        }
    }
}

// depth 2/3: gather Fin (read-only, L2-resident), bin-owned epilogue
__global__ __launch_bounds__(NTH) void pull_mid(
    const u32* __restrict__ binBuf, const u32* __restrict__ binCur,
    const u64* __restrict__ Fin, u64* __restrict__ Fout,
    u64* __restrict__ Vis, u64* __restrict__ CNT, int shift, int N) {
    __shared__ u64 NF[BIN_NODES];
    int tid = threadIdx.x, bin = blockIdx.x;
    if (tid < BIN_NODES) NF[tid] = 0ull;
    __syncthreads();
    u32 cnt = min(binCur[bin], (u32)CAPB);
    const u32* rb = binBuf + (size_t)bin * CAPB;
    const uint4* rb4 = (const uint4*)rb;
    u32 n4 = cnt >> 2;
    for (u32 i = tid; i < n4; i += NTH) {
        uint4 rr = rb4[i];
        u64 f0 = Fin[rr.x >> BIN_SH], f1 = Fin[rr.y >> BIN_SH];
        u64 f2 = Fin[rr.z >> BIN_SH], f3 = Fin[rr.w >> BIN_SH];
        if (f0) atomicOr(&NF[rr.x & (BIN_NODES - 1)], f0);
        if (f1) atomicOr(&NF[rr.y & (BIN_NODES - 1)], f1);
        if (f2) atomicOr(&NF[rr.z & (BIN_NODES - 1)], f2);
        if (f3) atomicOr(&NF[rr.w & (BIN_NODES - 1)], f3);
    }
    for (u32 r = (n4 << 2) + tid; r < cnt; r += NTH) {
        u32 a0 = rb[r];
        u64 f0 = Fin[a0 >> BIN_SH];
        if (f0) atomicOr(&NF[a0 & (BIN_NODES - 1)], f0);
    }
    __syncthreads();
    if (tid < BIN_NODES) {
        int n = bin * BIN_NODES + tid;
        if (n < N) {
            u64 vis = Vis[n];
            u64 nw = NF[tid] & ~vis;
            Fout[n] = nw;
            Vis[n] = vis | nw;
            CNT[n] += (u64)__popcll(nw) << shift;
        }
    }
}

// depth 4 + matmul epilogue (2 threads/node, D=16)
__global__ __launch_bounds__(NTH) void pull4fin(
    const u32* __restrict__ binBuf, const u32* __restrict__ binCur,
    const u64* __restrict__ Fin, const u64* __restrict__ Vis,
    const u64* __restrict__ CNT,
    const int* __restrict__ h, const int* __restrict__ t,
    const int* __restrict__ anchor, int A,
    const float* __restrict__ embed, float* __restrict__ out, int N) {
    __shared__ u64 NF[BIN_NODES];
    __shared__ float cds[BIN_NODES][8];
    __shared__ int nvs;
    int tid = threadIdx.x, bin = blockIdx.x;
    if (tid < BIN_NODES) NF[tid] = 0ull;
    if (tid < 64) {   // wave 0: recompute nvalid via shfl dedup
        int K = 2 * A;
        int a_ = (tid < K) ? anchor[(tid < A) ? tid : (tid - A)] : 0;
        int my = (tid < K) ? ((tid < A) ? h[a_] : t[a_]) : -1;
        bool uniq = (tid < K);
        for (int j = 0; j < 64; ++j) {
            int o = __shfl(my, j, 64);
            if (j < tid && o == my) uniq = false;
        }
        u64 mask = __ballot(uniq);
        if (tid == 0) nvs = (int)__popcll(mask);
    }
    __syncthreads();
    u32 cnt = min(binCur[bin], (u32)CAPB);
    const u32* rb = binBuf + (size_t)bin * CAPB;
    const uint4* rb4 = (const uint4*)rb;
    u32 n4 = cnt >> 2;
    for (u32 i = tid; i < n4; i += NTH) {
        uint4 rr = rb4[i];
        u64 f0 = Fin[rr.x >> BIN_SH], f1 = Fin[rr.y >> BIN_SH];
        u64 f2 = Fin[rr.z >> BIN_SH], f3 = Fin[rr.w >> BIN_SH];
        if (f0) atomicOr(&NF[rr.x & (BIN_NODES - 1)], f0);
        if (f1) atomicOr(&NF[rr.y & (BIN_NODES - 1)], f1);
        if (f2) atomicOr(&NF[rr.z & (BIN_NODES - 1)], f2);
        if (f3) atomicOr(&NF[rr.w & (BIN_NODES - 1)], f3);
    }
    for (u32 r = (n4 << 2) + tid; r < cnt; r += NTH) {
        u32 a0 = rb[r];
        u64 f0 = Fin[a0 >> BIN_SH];
        if (f0) atomicOr(&NF[a0 & (BIN_NODES - 1)], f0);
    }
    __syncthreads();
    int nv = nvs;
    if (tid < BIN_NODES) {
        int n = bin * BIN_NODES + tid;
        if (n < N) {
            u64 nw4 = NF[tid] & ~Vis[n];
            u64 c = CNT[n];
            int c0 = (int)(c & 0xffull), c1 = (int)((c >> 8) & 0xffull);
            int c2 = (int)((c >> 16) & 0xffull), c3 = (int)((c >> 24) & 0xffull);
            int c4 = __popcll(nw4);
            cds[tid][0] = (float)c0; cds[tid][1] = (float)c1;
            cds[tid][2] = (float)c2; cds[tid][3] = (float)c3;
            cds[tid][4] = (float)c4;
            cds[tid][5] = (float)(nv - (c0 + c1 + c2 + c3 + c4));
        }
    }
    __syncthreads();
    int nl = tid >> 1, q = tid & 1;   // 128 nodes x 2 half-rows (8 floats)
    int n = bin * BIN_NODES + nl;
    if (n >= N) return;
    float inv = 1.0f / (float)(nv > 0 ? nv : 1);
    const float4* e4 = (const float4*)embed;   // [6][4] float4 rows
    float4 accA = {0.f, 0.f, 0.f, 0.f}, accB = {0.f, 0.f, 0.f, 0.f};
#pragma unroll
    for (int d = 0; d <= MAXD; ++d) {
        float cd = cds[nl][d];
        float4 ea = e4[d * 4 + q * 2], eb = e4[d * 4 + q * 2 + 1];
        accA.x += cd * ea.x; accA.y += cd * ea.y;
        accA.z += cd * ea.z; accA.w += cd * ea.w;
        accB.x += cd * eb.x; accB.y += cd * eb.y;
        accB.z += cd * eb.z; accB.w += cd * eb.w;
    }
    accA.x *= inv; accA.y *= inv; accA.z *= inv; accA.w *= inv;
    accB.x *= inv; accB.y *= inv; accB.z *= inv; accB.w *= inv;
    float4* o4 = (float4*)(out + (size_t)n * 16);
    o4[q * 2] = accA; o4[q * 2 + 1] = accB;
}

extern "C" void kernel_launch(void* const* d_in, const int* in_sizes, int n_in,
                              void* d_out, int out_size, void* d_ws, size_t ws_size,
                              hipStream_t stream) {
    const int*   h      = (const int*)d_in[0];
    const int*   t      = (const int*)d_in[1];
    const int*   anchor = (const int*)d_in[2];
    const float* embed  = (const float*)d_in[4];
    float*       out    = (float*)d_out;

    int E = in_sizes[0];
    int A = in_sizes[2];                    // 32 anchor triples -> 64 sources
    int D = in_sizes[4] / (MAXD + 1);       // 16
    int N = out_size / D;                   // 50000
    int NBIN = (N + BIN_NODES - 1) >> BIN_SH;   // 391
    int NBs  = (E + EPB - 1) / EPB;             // 391 sortA blocks
    (void)D;

    u32* binCur = (u32*)d_ws;               // [512]
    u64* Vis    = (u64*)(binCur + 512);
    u64* Fa     = Vis + N;
    u64* Fb     = Fa + N;
    u64* CNT    = Fb + N;
    u32* binBuf = (u32*)(CNT + N);          // [NBIN][CAPB]

    hipMemsetAsync(binCur, 0, 512 * 4, stream);

    sortA<<<NBs, NTH, 0, stream>>>(h, t, E, NBIN, binCur, binBuf);
    pull1<<<NBIN, NTH, 0, stream>>>(binBuf, binCur, h, t, anchor, A,
                                    Fa, Vis, CNT, N);
    pull_mid<<<NBIN, NTH, 0, stream>>>(binBuf, binCur, Fa, Fb, Vis, CNT, 16, N);
    pull_mid<<<NBIN, NTH, 0, stream>>>(binBuf, binCur, Fb, Fa, Vis, CNT, 24, N);
    pull4fin<<<NBIN, NTH, 0, stream>>>(binBuf, binCur, Fa, Vis, CNT,
                                       h, t, anchor, A, embed, out, N);
}